// Round 7
// baseline (421.724 us; speedup 1.0000x reference)
//
#include <hip/hip_runtime.h>
#include <stdint.h>

namespace {

typedef _Float16 f16x8 __attribute__((ext_vector_type(8)));
typedef float f32x16 __attribute__((ext_vector_type(16)));

__device__ __forceinline__ uint32_t pkrtz(float a, float b) {
  return __builtin_bit_cast(uint32_t, __builtin_amdgcn_cvt_pkrtz(a, b));
}

constexpr int IMG = 512, K = 51;
constexpr int NT = 256;     // 4 waves: (group g) x (row parity)
constexpr int XB = 64;      // pixels per block
constexpr int YB = 8;       // output rows per block
constexpr int NSS = YB / 2; // 4 supersteps
constexpr int FSLOTS = 52;  // frame row ring
constexpr int FG = 16;      // 16B granules per channel-row = 128 f16 cols
constexpr int HP = 27;      // u32 pitch of H pair-table per x (26 pairs + pad)
constexpr int NQ = 6;       // K=16 chunks

// frame tile: [ch 3][granule 16][slot 52][8 f16] = 39936 B
// H table   : [par 2][x 64][27 u32]              = 13824 B  (total 53760 B)
constexpr int FR_U16 = 3 * FG * FSLOTS * 8;
constexpr int H_U32  = 2 * 64 * HP;
constexpr int CH_B   = FG * FSLOTS * 16;   // 13312 B per channel
constexpr int GR_B   = FSLOTS * 16;        // 832 B per granule

__global__ __launch_bounds__(NT, 3)       // 3 waves/EU min -> <=168 VGPR, 3 blk/CU
void sepconv(const float* __restrict__ fr0, const float* __restrict__ fr2,
             const float* __restrict__ V1, const float* __restrict__ H1,
             const float* __restrict__ V2, const float* __restrict__ H2,
             float* __restrict__ out)
{
  __shared__ __align__(16) uint16_t frL[FR_U16];
  __shared__ uint32_t hL[H_U32];
  uint32_t* fr32 = (uint32_t*)frL;

  const int tid = threadIdx.x;
  const int l   = tid & 63;
  const int w   = tid >> 6;
  const int g   = w & 1;       // 32-px group
  const int ypar= w >> 1;      // row parity of this wave
  const int n   = l & 31;      // pixel in group == A-row index
  const int kb  = l >> 5;      // k-half
  const int x0  = blockIdx.x * XB;
  const int y0  = blockIdx.y * YB;
  const int b   = blockIdx.z;
  const size_t plane = (size_t)IMG * IMG;
  const int xloc = 32 * g + n;

  // H staging role: (row parity hyy, pair-half hhalf) per wave, 64 x each
  const int hx = tid & 63, hhalf = (tid >> 6) & 1, hyy = (tid >> 7) & 1;
  const int p0h = 13 * hhalf;
  // steady frame-carry role: 2 rows x 3 ch x 64 pairs = 384 tasks
  const int rr0 = tid / 192, c0t = (tid % 192) / 64, pc0 = tid % 64;
  const bool has1 = tid < 128;
  const int t1 = tid + 256;
  const int rr1 = t1 / 192, c1t = (t1 % 192) / 64, pc1 = t1 % 64;
  const int sca0 = min(max(x0 - 25 + 2 * pc0, 0), IMG - 1);
  const int scb0 = min(max(x0 - 25 + 2 * pc0 + 1, 0), IMG - 1);
  const int sca1 = min(max(x0 - 25 + 2 * pc1, 0), IMG - 1);
  const int scb1 = min(max(x0 - 25 + 2 * pc1 + 1, 0), IMG - 1);

  #pragma unroll 1
  for (int f = 0; f < 2; ++f) {
    const float* __restrict__ fr = f ? fr2 : fr0;
    const float* __restrict__ Vf = (f ? V2 : V1) + (size_t)b * K * plane;
    const float* __restrict__ Hf = (f ? H2 : H1) + (size_t)b * K * plane;
    const float* __restrict__ frb = fr + (size_t)b * 3 * plane;

    float vA[27], vB[27];
    float ha[13], hb[13], fc[4];

    auto loadV = [&](int s, float (&v)[27]) {
      const int yw = y0 + 2 * s + ypar;
      const float* vb = Vf + (size_t)yw * IMG + x0 + xloc + (size_t)kb * 4 * plane;
      #pragma unroll
      for (int r = 0; r < 8; ++r)
        v[r] = vb[(size_t)((r & 3) + 8 * (r >> 2)) * plane];
      #pragma unroll
      for (int r = 0; r < 16; ++r)
        v[8 + r] = vb[(size_t)(19 + (r & 3) + 8 * (r >> 2)) * plane];
      if (kb == 0) {
        v[24] = vb[16 * plane]; v[25] = vb[17 * plane]; v[26] = vb[18 * plane];
      } else { v[24] = v[25] = v[26] = 0.f; }
    };
    auto loadCarry = [&](int s) {     // data for superstep s+1
      const int y = y0 + 2 * s;
      const int yH = y + 2 + hyy;     // <= 511 by construction
      #pragma unroll
      for (int m = 0; m < 13; ++m) {
        int p = p0h + m, j0 = 2 * p;
        ha[m] = Hf[(size_t)j0 * plane + (size_t)yH * IMG + x0 + hx];
        hb[m] = (j0 + 1 <= 50)
              ? Hf[(size_t)(j0 + 1) * plane + (size_t)yH * IMG + x0 + hx] : 0.f;
      }
      int row0 = min(y + 27 + rr0, IMG - 1);
      const float* rp0 = frb + (size_t)c0t * plane + (size_t)row0 * IMG;
      fc[0] = rp0[sca0]; fc[1] = rp0[scb0];
      if (has1) {
        int row1 = min(y + 27 + rr1, IMG - 1);
        const float* rp1 = frb + (size_t)c1t * plane + (size_t)row1 * IMG;
        fc[2] = rp1[sca1]; fc[3] = rp1[scb1];
      }
    };
    auto writeCarry = [&](int s) {    // at superstep s>=1
      const int y = y0 + 2 * s;
      int slot0 = (y + 25 + rr0 + 520) % 52;
      fr32[((c0t * FG + (pc0 >> 2)) * FSLOTS + slot0) * 4 + (pc0 & 3)] =
          pkrtz(fc[0], fc[1]);
      if (has1) {
        int slot1 = (y + 25 + rr1 + 520) % 52;
        fr32[((c1t * FG + (pc1 >> 2)) * FSLOTS + slot1) * 4 + (pc1 & 3)] =
            pkrtz(fc[2], fc[3]);
      }
      #pragma unroll
      for (int m = 0; m < 13; ++m)
        hL[(hyy * 64 + hx) * HP + p0h + m] = pkrtz(ha[m], hb[m]);
    };

    __syncthreads();   // previous pass's LDS reads complete

    // ---- prologue: H rows y0,y0+1 (26 loads batched) ----
    float pha[13], phb[13];
    {
      const int yH = y0 + hyy;
      #pragma unroll
      for (int m = 0; m < 13; ++m) {
        int p = p0h + m, j0 = 2 * p;
        pha[m] = Hf[(size_t)j0 * plane + (size_t)yH * IMG + x0 + hx];
        phb[m] = (j0 + 1 <= 50)
               ? Hf[(size_t)(j0 + 1) * plane + (size_t)yH * IMG + x0 + hx] : 0.f;
      }
    }
    // ---- prologue: frame rows y0-25..y0+26, 3 batched passes ----
    #pragma unroll 1
    for (int pass = 0; pass < 3; ++pass) {
      float ta[13], tb[13];
      #pragma unroll
      for (int k = 0; k < 13; ++k) {
        int task = tid + 256 * (pass * 13 + k);     // 256*39 = 9984 exact
        int rr = task / 192; int rem = task - rr * 192;
        int c = rem >> 6, pc = rem & 63;
        int row = min(max(y0 - 25 + rr, 0), IMG - 1);
        int ca = min(max(x0 - 25 + 2 * pc, 0), IMG - 1);
        int cb = min(max(x0 - 25 + 2 * pc + 1, 0), IMG - 1);
        const float* rp = frb + (size_t)c * plane + (size_t)row * IMG;
        ta[k] = rp[ca]; tb[k] = rp[cb];
      }
      if (pass == 0) {   // H-table write overlapped under pass-0 loads
        #pragma unroll
        for (int m = 0; m < 13; ++m)
          hL[(hyy * 64 + hx) * HP + p0h + m] = pkrtz(pha[m], phb[m]);
      }
      #pragma unroll
      for (int k = 0; k < 13; ++k) {
        int task = tid + 256 * (pass * 13 + k);
        int rr = task / 192; int rem = task - rr * 192;
        int c = rem >> 6, pc = rem & 63;
        int slot = (y0 - 25 + rr + 520) % 52;
        fr32[((c * FG + (pc >> 2)) * FSLOTS + slot) * 4 + (pc & 3)] =
            pkrtz(ta[k], tb[k]);
      }
    }
    loadV(0, vA);        // V[0] under prologue shadow
    __syncthreads();

    auto doSS = [&](int s, float (&vU)[27], float (&vN)[27]) {
      const int y = y0 + 2 * s;
      if (s > 0) {
        __syncthreads();
        writeCarry(s);
        __syncthreads();
      }
      const int yw = y + ypar;

      float op[3] = {0.f, 0.f, 0.f};
      if (f == 1 && l < 32) {
        #pragma unroll
        for (int c = 0; c < 3; ++c)
          op[c] = out[((size_t)(b * 3 + c) * IMG + yw) * IMG + x0 + xloc];
      }
      if (s + 1 < NSS) { loadV(s + 1, vN); loadCarry(s); }

      // ---- B fragments: banded per-pixel H (6 chunks of K=16) ----
      uint4 Bq[NQ];
      {
        const uint32_t* hrow = hL + (ypar * 64 + xloc) * HP;
        #pragma unroll
        for (int q = 0; q < NQ; ++q) {
          int j0 = 16 * q + 8 * kb - n;
          int pb = j0 >> 1;
          uint32_t rd[5];
          #pragma unroll
          for (int ww = 0; ww < 5; ++ww) {
            int pw = pb + ww;
            bool ok = (unsigned)pw <= 25u;
            uint32_t v = hrow[ok ? pw : 0];
            rd[ww] = ok ? v : 0u;
          }
          uint32_t fv[4];
          #pragma unroll
          for (int v2 = 0; v2 < 4; ++v2) {
            uint32_t al =
                (uint32_t)((((uint64_t)rd[v2 + 1] << 32) | rd[v2]) >> 16);
            fv[v2] = (n & 1) ? al : rd[v2];
          }
          Bq[q] = make_uint4(fv[0], fv[1], fv[2], fv[3]);
        }
      }

      // ---- A ring bases + MFMA + epilogue ----
      int sA = (yw - 25 + 520) % 52;
      int sB = (yw - 6 + 520) % 52;
      int slotA = sA + n; if (slotA >= 52) slotA -= 52;
      int slotB = sB + n; if (slotB >= 52) slotB -= 52;
      const char* pA0 = (const char*)frL + (4 * g + kb) * GR_B + slotA * 16;
      const char* pA1 = (const char*)frL + (4 * g + kb) * GR_B + slotB * 16;

      #pragma unroll
      for (int c = 0; c < 3; ++c) {
        f32x16 D0, D1;
        #pragma unroll
        for (int e = 0; e < 16; ++e) { D0[e] = 0.f; D1[e] = 0.f; }
        #pragma unroll
        for (int q = 0; q < NQ; ++q) {
          f16x8 A0 = *(const f16x8*)(pA0 + c * CH_B + q * (2 * GR_B));
          D0 = __builtin_amdgcn_mfma_f32_32x32x16_f16(
                   A0, __builtin_bit_cast(f16x8, Bq[q]), D0, 0, 0, 0);
          f16x8 A1 = *(const f16x8*)(pA1 + c * CH_B + q * (2 * GR_B));
          D1 = __builtin_amdgcn_mfma_f32_32x32x16_f16(
                   A1, __builtin_bit_cast(f16x8, Bq[q]), D1, 0, 0, 0);
        }
        float a = 0.f;
        #pragma unroll
        for (int r = 0; r < 8; ++r) a += vU[r] * D0[r];
        if (kb == 0) a += vU[24] * D0[8] + vU[25] * D0[9] + vU[26] * D0[10];
        #pragma unroll
        for (int r = 0; r < 16; ++r) a += vU[8 + r] * D1[r];
        a += __shfl_xor(a, 32, 64);
        if (l < 32) {
          size_t oidx = ((size_t)(b * 3 + c) * IMG + yw) * IMG + x0 + xloc;
          out[oidx] = (f == 0) ? a : (op[c] + a);
        }
      }
    };

    doSS(0, vA, vB);
    doSS(1, vB, vA);
    doSS(2, vA, vB);
    doSS(3, vB, vA);
  }
}

} // namespace

extern "C" void kernel_launch(void* const* d_in, const int* in_sizes, int n_in,
                              void* d_out, int out_size, void* d_ws, size_t ws_size,
                              hipStream_t stream)
{
  const float* frame0 = (const float*)d_in[0];
  const float* frame2 = (const float*)d_in[1];
  const float* V1 = (const float*)d_in[2];
  const float* H1 = (const float*)d_in[3];
  const float* V2 = (const float*)d_in[4];
  const float* H2 = (const float*)d_in[5];
  float* o = (float*)d_out;

  dim3 grid(IMG / XB, IMG / YB, 2);
  dim3 block(NT);
  hipLaunchKernelGGL(sepconv, grid, block, 0, stream,
                     frame0, frame2, V1, H1, V2, H2, o);
}

// Round 8
// 228.988 us; speedup vs baseline: 1.8417x; 1.8417x over previous
//
#include <hip/hip_runtime.h>
#include <stdint.h>

namespace {

typedef _Float16 f16x8 __attribute__((ext_vector_type(8)));
typedef float f32x16 __attribute__((ext_vector_type(16)));

__device__ __forceinline__ uint32_t pkrtz(float a, float b) {
  return __builtin_bit_cast(uint32_t, __builtin_amdgcn_cvt_pkrtz(a, b));
}

constexpr int IMG = 512, K = 51;
constexpr int NT = 256;     // 4 waves: (group g) x (row parity)
constexpr int XB = 64;      // pixels per block
constexpr int YB = 8;       // output rows per block
constexpr int NSS = YB / 2; // 4 supersteps
constexpr int FSLOTS = 52;  // frame row ring
constexpr int FG = 16;      // 16B granules per channel-row = 128 f16 cols
constexpr int HP = 27;      // u32 pitch of H pair-table per x (26 pairs + pad)
constexpr int NQ = 6;       // K=16 chunks

// frame tile: [ch 3][granule 16][slot 52][8 f16] = 39936 B
// H table   : [par 2][x 64][27 u32]              = 13824 B  (total 53760 B)
constexpr int FR_U16 = 3 * FG * FSLOTS * 8;
constexpr int H_U32  = 2 * 64 * HP;
constexpr int CH_B   = FG * FSLOTS * 16;   // 13312 B per channel
constexpr int GR_B   = FSLOTS * 16;        // 832 B per granule

__global__ __launch_bounds__(NT)
__attribute__((amdgpu_waves_per_eu(3, 3)))   // exact: 170-reg budget, 3 blk/CU
void sepconv(const float* __restrict__ fr0, const float* __restrict__ fr2,
             const float* __restrict__ V1, const float* __restrict__ H1,
             const float* __restrict__ V2, const float* __restrict__ H2,
             float* __restrict__ out)
{
  __shared__ __align__(16) uint16_t frL[FR_U16];
  __shared__ uint32_t hL[H_U32];
  uint32_t* fr32 = (uint32_t*)frL;

  const int tid = threadIdx.x;
  const int l   = tid & 63;
  const int w   = tid >> 6;
  const int g   = w & 1;       // 32-px group
  const int ypar= w >> 1;      // row parity of this wave
  const int n   = l & 31;      // pixel in group == A-row index
  const int kb  = l >> 5;      // k-half
  const int x0  = blockIdx.x * XB;
  const int y0  = blockIdx.y * YB;
  const int b   = blockIdx.z;
  const size_t plane = (size_t)IMG * IMG;
  const int xloc = 32 * g + n;

  // H staging role: (row parity hyy, pair-half hhalf) per wave, 64 x each
  const int hx = tid & 63, hhalf = (tid >> 6) & 1, hyy = (tid >> 7) & 1;
  const int p0h = 13 * hhalf;
  // steady frame-carry role: 2 rows x 3 ch x 64 pairs = 384 tasks
  const int rr0 = tid / 192, c0t = (tid % 192) / 64, pc0 = tid % 64;
  const bool has1 = tid < 128;
  const int t1 = tid + 256;
  const int rr1 = t1 / 192, c1t = (t1 % 192) / 64, pc1 = t1 % 64;
  const int sca0 = min(max(x0 - 25 + 2 * pc0, 0), IMG - 1);
  const int scb0 = min(max(x0 - 25 + 2 * pc0 + 1, 0), IMG - 1);
  const int sca1 = min(max(x0 - 25 + 2 * pc1, 0), IMG - 1);
  const int scb1 = min(max(x0 - 25 + 2 * pc1 + 1, 0), IMG - 1);

  #pragma unroll 1
  for (int f = 0; f < 2; ++f) {
    const float* __restrict__ fr = f ? fr2 : fr0;
    const float* __restrict__ Vf = (f ? V2 : V1) + (size_t)b * K * plane;
    const float* __restrict__ Hf = (f ? H2 : H1) + (size_t)b * K * plane;
    const float* __restrict__ frb = fr + (size_t)b * 3 * plane;

    float ha[13], hb[13], fc[4];     // distance-1 carries (next superstep)

    __syncthreads();   // previous pass's LDS reads complete

    // ---- prologue: H rows y0,y0+1 (26 loads batched) ----
    float pha[13], phb[13];
    {
      const int yH = y0 + hyy;
      #pragma unroll
      for (int m = 0; m < 13; ++m) {
        int p = p0h + m, j0 = 2 * p;
        pha[m] = Hf[(size_t)j0 * plane + (size_t)yH * IMG + x0 + hx];
        phb[m] = (j0 + 1 <= 50)
               ? Hf[(size_t)(j0 + 1) * plane + (size_t)yH * IMG + x0 + hx] : 0.f;
      }
    }
    // ---- prologue: frame rows y0-25..y0+26, 3 batched passes ----
    #pragma unroll 1
    for (int pass = 0; pass < 3; ++pass) {
      float ta[13], tb[13];
      #pragma unroll
      for (int k = 0; k < 13; ++k) {
        int task = tid + 256 * (pass * 13 + k);     // 256*39 = 9984 exact
        int rr = task / 192; int rem = task - rr * 192;
        int c = rem >> 6, pc = rem & 63;
        int row = min(max(y0 - 25 + rr, 0), IMG - 1);
        int ca = min(max(x0 - 25 + 2 * pc, 0), IMG - 1);
        int cb = min(max(x0 - 25 + 2 * pc + 1, 0), IMG - 1);
        const float* rp = frb + (size_t)c * plane + (size_t)row * IMG;
        ta[k] = rp[ca]; tb[k] = rp[cb];
      }
      if (pass == 0) {   // H-table write overlapped under pass-0 loads
        #pragma unroll
        for (int m = 0; m < 13; ++m)
          hL[(hyy * 64 + hx) * HP + p0h + m] = pkrtz(pha[m], phb[m]);
      }
      #pragma unroll
      for (int k = 0; k < 13; ++k) {
        int task = tid + 256 * (pass * 13 + k);
        int rr = task / 192; int rem = task - rr * 192;
        int c = rem >> 6, pc = rem & 63;
        int slot = (y0 - 25 + rr + 520) % 52;
        fr32[((c * FG + (pc >> 2)) * FSLOTS + slot) * 4 + (pc & 3)] =
            pkrtz(ta[k], tb[k]);
      }
    }
    __syncthreads();

    #pragma unroll 1
    for (int s = 0; s < NSS; ++s) {
      const int y = y0 + 2 * s;
      if (s > 0) {
        __syncthreads();
        // write carries loaded at superstep s-1 (latency fully covered)
        {
          int slot0 = (y + 25 + rr0 + 520) % 52;
          fr32[((c0t * FG + (pc0 >> 2)) * FSLOTS + slot0) * 4 + (pc0 & 3)] =
              pkrtz(fc[0], fc[1]);
          if (has1) {
            int slot1 = (y + 25 + rr1 + 520) % 52;
            fr32[((c1t * FG + (pc1 >> 2)) * FSLOTS + slot1) * 4 + (pc1 & 3)] =
                pkrtz(fc[2], fc[3]);
          }
          #pragma unroll
          for (int m = 0; m < 13; ++m)
            hL[(hyy * 64 + hx) * HP + p0h + m] = pkrtz(ha[m], hb[m]);
        }
        __syncthreads();
      }
      const int yw = y + ypar;

      // ---- V loads issued first (consumed in epilogue, >1500 cyc later) ----
      float v[27];
      {
        const float* vb =
            Vf + (size_t)yw * IMG + x0 + xloc + (size_t)kb * 4 * plane;
        #pragma unroll
        for (int r = 0; r < 8; ++r)
          v[r] = vb[(size_t)((r & 3) + 8 * (r >> 2)) * plane];
        #pragma unroll
        for (int r = 0; r < 16; ++r)
          v[8 + r] = vb[(size_t)(19 + (r & 3) + 8 * (r >> 2)) * plane];
        if (kb == 0) {
          v[24] = vb[16 * plane]; v[25] = vb[17 * plane]; v[26] = vb[18 * plane];
        } else { v[24] = v[25] = v[26] = 0.f; }
      }
      float op[3] = {0.f, 0.f, 0.f};
      if (f == 1 && l < 32) {
        #pragma unroll
        for (int c = 0; c < 3; ++c)
          op[c] = out[((size_t)(b * 3 + c) * IMG + yw) * IMG + x0 + xloc];
      }
      // ---- carry loads for superstep s+1 ----
      if (s + 1 < NSS) {
        const int yH = y + 2 + hyy;
        #pragma unroll
        for (int m = 0; m < 13; ++m) {
          int p = p0h + m, j0 = 2 * p;
          ha[m] = Hf[(size_t)j0 * plane + (size_t)yH * IMG + x0 + hx];
          hb[m] = (j0 + 1 <= 50)
                ? Hf[(size_t)(j0 + 1) * plane + (size_t)yH * IMG + x0 + hx] : 0.f;
        }
        int row0 = min(y + 27 + rr0, IMG - 1);
        const float* rp0 = frb + (size_t)c0t * plane + (size_t)row0 * IMG;
        fc[0] = rp0[sca0]; fc[1] = rp0[scb0];
        if (has1) {
          int row1 = min(y + 27 + rr1, IMG - 1);
          const float* rp1 = frb + (size_t)c1t * plane + (size_t)row1 * IMG;
          fc[2] = rp1[sca1]; fc[3] = rp1[scb1];
        }
      }

      // ---- B fragments: banded per-pixel H (6 chunks of K=16) ----
      uint4 Bq[NQ];
      {
        const uint32_t* hrow = hL + (ypar * 64 + xloc) * HP;
        #pragma unroll
        for (int q = 0; q < NQ; ++q) {
          int j0 = 16 * q + 8 * kb - n;
          int pb = j0 >> 1;
          uint32_t rd[5];
          #pragma unroll
          for (int ww = 0; ww < 5; ++ww) {
            int pw = pb + ww;
            bool ok = (unsigned)pw <= 25u;
            uint32_t vr = hrow[ok ? pw : 0];
            rd[ww] = ok ? vr : 0u;
          }
          uint32_t fv[4];
          #pragma unroll
          for (int v2 = 0; v2 < 4; ++v2) {
            uint32_t al =
                (uint32_t)((((uint64_t)rd[v2 + 1] << 32) | rd[v2]) >> 16);
            fv[v2] = (n & 1) ? al : rd[v2];
          }
          Bq[q] = make_uint4(fv[0], fv[1], fv[2], fv[3]);
        }
      }

      // ---- A ring bases + MFMA + epilogue ----
      int sA = (yw - 25 + 520) % 52;
      int sB = (yw - 6 + 520) % 52;
      int slotA = sA + n; if (slotA >= 52) slotA -= 52;
      int slotB = sB + n; if (slotB >= 52) slotB -= 52;
      const char* pA0 = (const char*)frL + (4 * g + kb) * GR_B + slotA * 16;
      const char* pA1 = (const char*)frL + (4 * g + kb) * GR_B + slotB * 16;

      #pragma unroll
      for (int c = 0; c < 3; ++c) {
        f32x16 D0, D1;
        #pragma unroll
        for (int e = 0; e < 16; ++e) { D0[e] = 0.f; D1[e] = 0.f; }
        #pragma unroll
        for (int q = 0; q < NQ; ++q) {
          f16x8 A0 = *(const f16x8*)(pA0 + c * CH_B + q * (2 * GR_B));
          D0 = __builtin_amdgcn_mfma_f32_32x32x16_f16(
                   A0, __builtin_bit_cast(f16x8, Bq[q]), D0, 0, 0, 0);
          f16x8 A1 = *(const f16x8*)(pA1 + c * CH_B + q * (2 * GR_B));
          D1 = __builtin_amdgcn_mfma_f32_32x32x16_f16(
                   A1, __builtin_bit_cast(f16x8, Bq[q]), D1, 0, 0, 0);
        }
        float a = 0.f;
        #pragma unroll
        for (int r = 0; r < 8; ++r) a += v[r] * D0[r];
        if (kb == 0) a += v[24] * D0[8] + v[25] * D0[9] + v[26] * D0[10];
        #pragma unroll
        for (int r = 0; r < 16; ++r) a += v[8 + r] * D1[r];
        a += __shfl_xor(a, 32, 64);
        if (l < 32) {
          size_t oidx = ((size_t)(b * 3 + c) * IMG + yw) * IMG + x0 + xloc;
          out[oidx] = (f == 0) ? a : (op[c] + a);
        }
      }
    }
  }
}

} // namespace

extern "C" void kernel_launch(void* const* d_in, const int* in_sizes, int n_in,
                              void* d_out, int out_size, void* d_ws, size_t ws_size,
                              hipStream_t stream)
{
  const float* frame0 = (const float*)d_in[0];
  const float* frame2 = (const float*)d_in[1];
  const float* V1 = (const float*)d_in[2];
  const float* H1 = (const float*)d_in[3];
  const float* V2 = (const float*)d_in[4];
  const float* H2 = (const float*)d_in[5];
  float* o = (float*)d_out;

  dim3 grid(IMG / XB, IMG / YB, 2);
  dim3 block(NT);
  hipLaunchKernelGGL(sepconv, grid, block, 0, stream,
                     frame0, frame2, V1, H1, V2, H2, o);
}